// Round 11
// baseline (68.275 us; speedup 1.0000x reference)
//
#include <hip/hip_runtime.h>
#include <hip/hip_fp16.h>

#define IMG 192
#define ROWP 196       // LDS row stride (floats); odd-stride reads stay ≤2-way
#define CS1H 2359296   // B1h halves per channel = 36864*64
// B1h: [5][zy=36864][64] halves = 23.6 MB
// B2h: [5][z=192][oy=57][64] halves = 7.0 MB
// B3 : [5][oz=57][oy=57][64] fp32  = 4.2 MB
// partials[269]: [0,204) scale0, [204,266) scale1, [266,269) scale2.

__device__ __forceinline__ float2 h2f(unsigned int u) {
    __half2 h = *reinterpret_cast<const __half2*>(&u);
    return __half22float2(h);
}
__device__ __forceinline__ unsigned int f2h(float a, float b) {
    __half2 h = __floats2half2_rn(a, b);
    return *reinterpret_cast<const unsigned int*>(&h);
}

// ---------------------------------------------------------------------------
// Pass 1 (x): 8 rows/block in LDS, 1 output/thread (stride-3 reads: ≤2-way
// bank aliasing, free), fp16 scalar stores into 64-padded rows.
// ---------------------------------------------------------------------------
__global__ __launch_bounds__(256) void pass1_s0(
    const float* __restrict__ I, const float* __restrict__ T,
    __half* __restrict__ B1h)
{
    __shared__ float lI[8 * ROWP];
    __shared__ float lT[8 * ROWP];
    const int tid = threadIdx.x;
    const int r0  = blockIdx.x * 8;

    const float4* I4 = (const float4*)(I + (size_t)r0 * IMG);
    const float4* T4 = (const float4*)(T + (size_t)r0 * IMG);
    float4* lI4 = (float4*)lI;
    float4* lT4 = (float4*)lT;
    for (int t = tid; t < 8 * 48; t += 256) {
        int row = t / 48, xi = t - row * 48;
        lI4[row * (ROWP / 4) + xi] = I4[t];
        lT4[row * (ROWP / 4) + xi] = T4[t];
    }
    __syncthreads();

    for (int w = tid; w < 8 * 57; w += 256) {
        int row = w / 57, ox = w - row * 57;
        const float* a = &lI[row * ROWP + ox * 3];
        const float* b = &lT[row * ROWP + ox * 3];
        float sI = 0.f, sT = 0.f, sI2 = 0.f, sT2 = 0.f, sIT = 0.f;
#pragma unroll
        for (int i = 0; i < 12; ++i) {
            float x = a[2 * i], y = b[2 * i];
            sI += x; sT += y; sI2 += x * x; sT2 += y * y; sIT += x * y;
        }
        size_t o = (size_t)(r0 + row) * 64 + ox;
        B1h[o]             = __float2half_rn(sI);
        B1h[CS1H + o]      = __float2half_rn(sT);
        B1h[2 * CS1H + o]  = __float2half_rn(sI2);
        B1h[3 * CS1H + o]  = __float2half_rn(sT2);
        B1h[4 * CS1H + o]  = __float2half_rn(sIT);
    }
}

// ---------------------------------------------------------------------------
// Pass 2 (y): uint4 (8 halves = 16B/lane) in, fp32 accumulate, uint4 out.
// Exact grid: 5*192*57*8 / 256 = 1710 blocks.
// ---------------------------------------------------------------------------
__global__ __launch_bounds__(256) void passY_s0(
    const __half* __restrict__ B1h, uint4* __restrict__ B2h4)
{
    constexpr int CV8 = IMG * 57 * 8;       // 87552 uint4 per channel
    int idx = blockIdx.x * 256 + threadIdx.x;   // < 5*CV8 exactly
    int c   = idx / CV8;
    int r   = idx - c * CV8;
    int ox8 = r & 7;
    int t   = r >> 3;
    int oy  = t % 57;
    int z   = t / 57;
    const uint4* p = (const uint4*)(B1h + (size_t)c * CS1H
                      + ((size_t)z * IMG + (size_t)oy * 3) * 64) + ox8;
    float acc[8] = {0.f, 0.f, 0.f, 0.f, 0.f, 0.f, 0.f, 0.f};
#pragma unroll
    for (int j = 0; j < 12; ++j) {
        uint4 u = p[(size_t)j * 16];        // 2 rows * 8 uint4
        float2 f;
        f = h2f(u.x); acc[0] += f.x; acc[1] += f.y;
        f = h2f(u.y); acc[2] += f.x; acc[3] += f.y;
        f = h2f(u.z); acc[4] += f.x; acc[5] += f.y;
        f = h2f(u.w); acc[6] += f.x; acc[7] += f.y;
    }
    uint4 o;
    o.x = f2h(acc[0], acc[1]);
    o.y = f2h(acc[2], acc[3]);
    o.z = f2h(acc[4], acc[5]);
    o.w = f2h(acc[6], acc[7]);
    B2h4[idx] = o;
}

// ---------------------------------------------------------------------------
// Pass 3 (z), per channel: 12 uint4 loads, fp32 accumulate, 2 float4 stores.
// Also zeroes the red_all counter. 508 blocks.
// ---------------------------------------------------------------------------
__global__ __launch_bounds__(256) void passZc(
    const uint4* __restrict__ B2h4, float4* __restrict__ B3v,
    unsigned int* __restrict__ counter)
{
    constexpr int N3V8 = 57 * 57 * 8;       // 25992 uint4 per channel
    int idx = blockIdx.x * 256 + threadIdx.x;
    if (blockIdx.x == 0 && threadIdx.x == 0) counter[0] = 0u;
    if (idx >= 5 * N3V8) return;
    int c   = idx / N3V8;
    int rv  = idx - c * N3V8;
    int ox8 = rv & 7;
    int t   = rv >> 3;
    int oy  = t % 57;
    int oz  = t / 57;
    const uint4* p = B2h4 + ((size_t)(c * IMG + 3 * oz) * 57 + oy) * 8 + ox8;
    float acc[8] = {0.f, 0.f, 0.f, 0.f, 0.f, 0.f, 0.f, 0.f};
#pragma unroll
    for (int l = 0; l < 12; ++l) {
        uint4 u = p[(size_t)l * 912];       // 2*57*8
        float2 f;
        f = h2f(u.x); acc[0] += f.x; acc[1] += f.y;
        f = h2f(u.y); acc[2] += f.x; acc[3] += f.y;
        f = h2f(u.z); acc[4] += f.x; acc[5] += f.y;
        f = h2f(u.w); acc[6] += f.x; acc[7] += f.y;
    }
    size_t o = ((size_t)(c * 57 + oz) * 57 + oy) * 16 + ox8 * 2;
    B3v[o]     = make_float4(acc[0], acc[1], acc[2], acc[3]);
    B3v[o + 1] = make_float4(acc[4], acc[5], acc[6], acc[7]);
}

// ---------------------------------------------------------------------------
__device__ __forceinline__ float lncc1(float i_s, float t_s, float i2, float t2,
                                       float it, float inv_numel) {
    float cross = it - i_s * t_s * inv_numel;
    float iv    = i2 - i_s * i_s * inv_numel;
    float tv    = t2 - t_s * t_s * inv_numel;
    return cross * cross / (iv * tv + 1e-5f);
}

template<int DN, int M>
__device__ __forceinline__ float derive_lncc(const float* __restrict__ B3,
                                             int r, int O1,
                                             float inv_numel, float wdiv) {
    int ox = r % O1;
    int t  = r / O1;
    int oy = t % O1;
    int oz = t / O1;
    float s[5];
    for (int c = 0; c < 5; ++c) {
        float acc = 0.f;
        for (int iz = 0; iz < DN; ++iz)
            for (int iy = 0; iy < DN; ++iy) {
                const float* p = B3
                    + (((size_t)(c * 57) + (M * oz + 8 * iz)) * 57
                       + (M * oy + 8 * iy)) * 64 + M * ox;
#pragma unroll
                for (int ix = 0; ix < DN; ++ix) acc += p[8 * ix];
            }
        s[c] = acc;
    }
    return wdiv * lncc1(s[0], s[1], s[2], s[3], s[4], inv_numel);
}

// ---------------------------------------------------------------------------
// red_all: scale0 LNCC from B3 (float4), scale1/2 nested gathers, counter
// finalize. 269 blocks total: [0,204) s0, [204,266) s1, [266,269) s2.
// ---------------------------------------------------------------------------
__global__ __launch_bounds__(256) void red_all(
    const float* __restrict__ B3, float* __restrict__ partials,
    unsigned int* __restrict__ counter, float* __restrict__ out)
{
    constexpr int N3V4 = 57 * 57 * 16;      // 51984 float4 per channel
    const int b = blockIdx.x;
    float v = 0.f;
    if (b < 204) {
        int rv = b * 256 + threadIdx.x;
        if (rv < N3V4) {
            const float4* p = (const float4*)B3;
            float4 s0 = p[rv];
            float4 s1 = p[(size_t)1 * N3V4 + rv];
            float4 s2 = p[(size_t)2 * N3V4 + rv];
            float4 s3 = p[(size_t)3 * N3V4 + rv];
            float4 s4 = p[(size_t)4 * N3V4 + rv];
            const float inv_numel = 1.f / 1728.f;
            int ox = (rv & 15) * 4;
            if (ox + 0 < 57) v += lncc1(s0.x, s1.x, s2.x, s3.x, s4.x, inv_numel);
            if (ox + 1 < 57) v += lncc1(s0.y, s1.y, s2.y, s3.y, s4.y, inv_numel);
            if (ox + 2 < 57) v += lncc1(s0.z, s1.z, s2.z, s3.z, s4.z, inv_numel);
            if (ox + 3 < 57) v += lncc1(s0.w, s1.w, s2.w, s3.w, s4.w, inv_numel);
            v *= 0.1f / 185193.f;
        }
    } else if (b < 266) {
        int r = (b - 204) * 256 + threadIdx.x;
        if (r < 15625)
            v = derive_lncc<2, 2>(B3, r, 25, 1.f / 13824.f, 0.3f / 15625.f);
    } else {
        int r = (b - 266) * 256 + threadIdx.x;
        if (r < 729)
            v = derive_lncc<4, 4>(B3, r, 9, 1.f / 110592.f, 0.6f / 729.f);
    }
    __shared__ float red[256];
    red[threadIdx.x] = v;
    __syncthreads();
    for (int o = 128; o > 0; o >>= 1) {
        if (threadIdx.x < o) red[threadIdx.x] += red[threadIdx.x + o];
        __syncthreads();
    }
    if (threadIdx.x == 0) partials[b] = red[0];

    __threadfence();
    __shared__ unsigned int lastFlag;
    if (threadIdx.x == 0)
        lastFlag = (atomicAdd(counter, 1u) == 268u) ? 1u : 0u;
    __syncthreads();
    if (lastFlag) {
        __threadfence();
        float w = 0.f;
        for (int i = threadIdx.x; i < 269; i += 256) w += partials[i];
        red[threadIdx.x] = w;
        __syncthreads();
        for (int o = 128; o > 0; o >>= 1) {
            if (threadIdx.x < o) red[threadIdx.x] += red[threadIdx.x + o];
            __syncthreads();
        }
        if (threadIdx.x == 0) out[0] = 1.0f - red[0];
    }
}

// ------------------- fallback kernels (small-ws path, fp32) ----------------
__global__ void pass1_one(const float* __restrict__ I, const float* __restrict__ T,
                          float* __restrict__ B1, int O, int s, int k, int c) {
    int idx = blockIdx.x * blockDim.x + threadIdx.x;
    if (idx >= IMG * IMG * O) return;
    int ox = idx % O;
    int zy = idx / O;
    const float* pI = I + (size_t)zy * IMG + ox * s;
    const float* pT = T + (size_t)zy * IMG + ox * s;
    float acc = 0.f;
    for (int i = 0; i < k; ++i) {
        float v;
        if (c == 0)      v = pI[2 * i];
        else if (c == 1) v = pT[2 * i];
        else if (c == 2) { float a = pI[2 * i]; v = a * a; }
        else if (c == 3) { float bb = pT[2 * i]; v = bb * bb; }
        else             { v = pI[2 * i] * pT[2 * i]; }
        acc += v;
    }
    B1[idx] = acc;
}

__global__ void pass_y(const float* __restrict__ Bin, float* __restrict__ Bout,
                       int O, int s, int k, int n1, int n2) {
    int idx = blockIdx.x * blockDim.x + threadIdx.x;
    if (idx >= n2) return;
    int ox = idx % O;
    int t  = idx / O;
    int oy = t % O;
    int z  = t / O;
    const float* p = Bin + (size_t)z * IMG * O + (size_t)(oy * s) * O + ox;
    float acc = 0.f;
    for (int j = 0; j < k; ++j) acc += p[(size_t)j * 2 * O];
    Bout[idx] = acc;
}

__global__ void pass_z(const float* __restrict__ Bin, float* __restrict__ Bout,
                       int O, int s, int k, int n2, int n3) {
    int idx = blockIdx.x * blockDim.x + threadIdx.x;
    if (idx >= n3) return;
    int ox = idx % O;
    int t  = idx / O;
    int oy = t % O;
    int oz = t / O;
    const float* p = Bin + (size_t)(oz * s) * O * O + (size_t)oy * O + ox;
    float acc = 0.f;
    for (int l = 0; l < k; ++l) acc += p[(size_t)l * 2 * O * O];
    Bout[idx] = acc;
}

__global__ void reduce_one(const float* __restrict__ B3, int n3, float inv_numel,
                           float wdiv, float* __restrict__ partials) {
    float local = 0.f;
    for (int i = blockIdx.x * 256 + threadIdx.x; i < n3; i += gridDim.x * 256) {
        float i_s = B3[i];
        float t_s = B3[(size_t)n3 + i];
        float i2  = B3[2 * (size_t)n3 + i];
        float t2  = B3[3 * (size_t)n3 + i];
        float it  = B3[4 * (size_t)n3 + i];
        local += wdiv * lncc1(i_s, t_s, i2, t2, it, inv_numel);
    }
    __shared__ float red[256];
    red[threadIdx.x] = local;
    __syncthreads();
    for (int o = 128; o > 0; o >>= 1) {
        if (threadIdx.x < o) red[threadIdx.x] += red[threadIdx.x + o];
        __syncthreads();
    }
    if (threadIdx.x == 0) partials[blockIdx.x] += red[0];
}

__global__ void finalize_n(const float* __restrict__ partials, int n,
                           float* __restrict__ out) {
    float v = 0.f;
    for (int i = threadIdx.x; i < n; i += 256) v += partials[i];
    __shared__ float red[256];
    red[threadIdx.x] = v;
    __syncthreads();
    for (int o = 128; o > 0; o >>= 1) {
        if (threadIdx.x < o) red[threadIdx.x] += red[threadIdx.x + o];
        __syncthreads();
    }
    if (threadIdx.x == 0) out[0] = 1.0f - red[0];
}

__global__ void zero_buf(float* __restrict__ p, int n) {
    int i = blockIdx.x * 256 + threadIdx.x;
    if (i < n) p[i] = 0.f;
}

// ---------------------------------------------------------------------------
extern "C" void kernel_launch(void* const* d_in, const int* in_sizes, int n_in,
                              void* d_out, int out_size, void* d_ws, size_t ws_size,
                              hipStream_t stream) {
    const float* I = (const float*)d_in[0];
    const float* T = (const float*)d_in[1];
    float* out = (float*)d_out;
    float* ws  = (float*)d_ws;

    const size_t szB1f = 5898240;    // B1h as float-equivalents (23.6 MB)
    const size_t szB2f = 1751040;    // B2h as float-equivalents (7.0 MB)
    const size_t szB3  = 1039680;    // fp32 (4.2 MB)
    const size_t need  = (szB1f + szB2f + szB3 + 512) * sizeof(float); // ~35 MB

    if (ws_size >= need) {
        __half* B1h  = (__half*)ws;
        uint4*  B2h4 = (uint4*)(ws + szB1f);
        float*  B3   = ws + szB1f + szB2f;
        float*  partials = B3 + szB3;
        unsigned int* counter = (unsigned int*)(partials + 280);
        pass1_s0<<<4608, 256, 0, stream>>>(I, T, B1h);
        passY_s0<<<1710, 256, 0, stream>>>(B1h, B2h4);
        passZc<<<508, 256, 0, stream>>>(B2h4, (float4*)B3, counter);
        red_all<<<269, 256, 0, stream>>>(B3, partials, counter, out);
    } else {
        const int   Ks[3] = {12, 24, 48};
        const int   Ss[3] = {3, 6, 12};
        const int   Os[3] = {57, 25, 9};
        const int   N1[3] = {2101248, 921600, 331776};
        const int   N2[3] = {623808, 120000, 15552};
        const int   N3[3] = {185193, 15625, 729};
        const float Wt[3] = {0.1f, 0.3f, 0.6f};

        float* B1 = ws;
        float* B2 = B1 + 2101248;
        float* B3 = B2 + 623808;
        float* partials = B3 + 925965;

        zero_buf<<<1, 256, 0, stream>>>(partials, 256);
        for (int sc = 0; sc < 3; ++sc) {
            int k = Ks[sc], s = Ss[sc], O = Os[sc];
            int n1 = N1[sc], n2 = N2[sc], n3 = N3[sc];
            for (int c = 0; c < 5; ++c) {
                pass1_one<<<(n1 + 255) / 256, 256, 0, stream>>>(I, T, B1, O, s, k, c);
                pass_y<<<(n2 + 255) / 256, 256, 0, stream>>>(B1, B2, O, s, k, n1, n2);
                pass_z<<<(n3 + 255) / 256, 256, 0, stream>>>(B2, B3 + (size_t)c * n3, O, s, k, n2, n3);
            }
            int nblk = (n3 + 255) / 256; if (nblk > 256) nblk = 256;
            reduce_one<<<nblk, 256, 0, stream>>>(B3, n3, 1.f / ((float)k * k * k),
                                                 Wt[sc] / (float)n3, partials);
        }
        finalize_n<<<1, 256, 0, stream>>>(partials, 256, out);
    }
}

// Round 12
// 43.813 us; speedup vs baseline: 1.5583x; 1.5583x over previous
//
#include <hip/hip_runtime.h>
#include <hip/hip_fp16.h>

#define IMG 192
#define ROWP 196       // LDS row stride (floats)
#define CS1H 2359296   // B1h halves per channel = 36864*64
// B1h: [5][zy=36864][64] halves = 23.6 MB
// B2h: [5][z=192][oy=57][64] halves = 7.0 MB
// B3 : [5][oz=57][oy=57][64] fp32  = 4.2 MB
// partials[572]: [0,204) red0, [204,511) red1, [511,572) red2.

__device__ __forceinline__ float2 h2f(unsigned int u) {
    __half2 h = *reinterpret_cast<const __half2*>(&u);
    return __half22float2(h);
}
__device__ __forceinline__ unsigned int f2h(float a, float b) {
    __half2 h = __floats2half2_rn(a, b);
    return *reinterpret_cast<const unsigned int*>(&h);
}

// ---------------------------------------------------------------------------
// Pass 1 (x): 8 rows/block in LDS, 1 output/thread, fp16 stores, 64-pad rows.
// ---------------------------------------------------------------------------
__global__ __launch_bounds__(256) void pass1_s0(
    const float* __restrict__ I, const float* __restrict__ T,
    __half* __restrict__ B1h)
{
    __shared__ float lI[8 * ROWP];
    __shared__ float lT[8 * ROWP];
    const int tid = threadIdx.x;
    const int r0  = blockIdx.x * 8;

    const float4* I4 = (const float4*)(I + (size_t)r0 * IMG);
    const float4* T4 = (const float4*)(T + (size_t)r0 * IMG);
    float4* lI4 = (float4*)lI;
    float4* lT4 = (float4*)lT;
    for (int t = tid; t < 8 * 48; t += 256) {
        int row = t / 48, xi = t - row * 48;
        lI4[row * (ROWP / 4) + xi] = I4[t];
        lT4[row * (ROWP / 4) + xi] = T4[t];
    }
    __syncthreads();

    for (int w = tid; w < 8 * 57; w += 256) {
        int row = w / 57, ox = w - row * 57;
        const float* a = &lI[row * ROWP + ox * 3];
        const float* b = &lT[row * ROWP + ox * 3];
        float sI = 0.f, sT = 0.f, sI2 = 0.f, sT2 = 0.f, sIT = 0.f;
#pragma unroll
        for (int i = 0; i < 12; ++i) {
            float x = a[2 * i], y = b[2 * i];
            sI += x; sT += y; sI2 += x * x; sT2 += y * y; sIT += x * y;
        }
        size_t o = (size_t)(r0 + row) * 64 + ox;
        B1h[o]             = __float2half_rn(sI);
        B1h[CS1H + o]      = __float2half_rn(sT);
        B1h[2 * CS1H + o]  = __float2half_rn(sI2);
        B1h[3 * CS1H + o]  = __float2half_rn(sT2);
        B1h[4 * CS1H + o]  = __float2half_rn(sIT);
    }
}

// ---------------------------------------------------------------------------
// Pass 2 (y): uint4 (8 halves) in, fp32 accumulate, uint4 out. 1710 blocks.
// ---------------------------------------------------------------------------
__global__ __launch_bounds__(256) void passY_s0(
    const __half* __restrict__ B1h, uint4* __restrict__ B2h4)
{
    constexpr int CV8 = IMG * 57 * 8;       // 87552 uint4 per channel
    int idx = blockIdx.x * 256 + threadIdx.x;   // == 5*CV8 exactly
    int c   = idx / CV8;
    int r   = idx - c * CV8;
    int ox8 = r & 7;
    int t   = r >> 3;
    int oy  = t % 57;
    int z   = t / 57;
    const uint4* p = (const uint4*)(B1h + (size_t)c * CS1H
                      + ((size_t)z * IMG + (size_t)oy * 3) * 64) + ox8;
    float acc[8] = {0.f, 0.f, 0.f, 0.f, 0.f, 0.f, 0.f, 0.f};
#pragma unroll
    for (int j = 0; j < 12; ++j) {
        uint4 u = p[(size_t)j * 16];
        float2 f;
        f = h2f(u.x); acc[0] += f.x; acc[1] += f.y;
        f = h2f(u.y); acc[2] += f.x; acc[3] += f.y;
        f = h2f(u.z); acc[4] += f.x; acc[5] += f.y;
        f = h2f(u.w); acc[6] += f.x; acc[7] += f.y;
    }
    uint4 o;
    o.x = f2h(acc[0], acc[1]);
    o.y = f2h(acc[2], acc[3]);
    o.z = f2h(acc[4], acc[5]);
    o.w = f2h(acc[6], acc[7]);
    B2h4[idx] = o;
}

// ---------------------------------------------------------------------------
// Pass 3 (z): per channel, 12 uint4 loads, 2 float4 stores. 508 blocks.
// ---------------------------------------------------------------------------
__global__ __launch_bounds__(256) void passZc(
    const uint4* __restrict__ B2h4, float4* __restrict__ B3v)
{
    constexpr int N3V8 = 57 * 57 * 8;       // 25992 uint4 per channel
    int idx = blockIdx.x * 256 + threadIdx.x;
    if (idx >= 5 * N3V8) return;
    int c   = idx / N3V8;
    int rv  = idx - c * N3V8;
    int ox8 = rv & 7;
    int t   = rv >> 3;
    int oy  = t % 57;
    int oz  = t / 57;
    const uint4* p = B2h4 + ((size_t)(c * IMG + 3 * oz) * 57 + oy) * 8 + ox8;
    float acc[8] = {0.f, 0.f, 0.f, 0.f, 0.f, 0.f, 0.f, 0.f};
#pragma unroll
    for (int l = 0; l < 12; ++l) {
        uint4 u = p[(size_t)l * 912];       // 2*57*8
        float2 f;
        f = h2f(u.x); acc[0] += f.x; acc[1] += f.y;
        f = h2f(u.y); acc[2] += f.x; acc[3] += f.y;
        f = h2f(u.z); acc[4] += f.x; acc[5] += f.y;
        f = h2f(u.w); acc[6] += f.x; acc[7] += f.y;
    }
    size_t o = ((size_t)(c * 57 + oz) * 57 + oy) * 16 + ox8 * 2;
    B3v[o]     = make_float4(acc[0], acc[1], acc[2], acc[3]);
    B3v[o + 1] = make_float4(acc[4], acc[5], acc[6], acc[7]);
}

// ---------------------------------------------------------------------------
__device__ __forceinline__ float lncc1(float i_s, float t_s, float i2, float t2,
                                       float it, float inv_numel) {
    float cross = it - i_s * t_s * inv_numel;
    float iv    = i2 - i_s * i_s * inv_numel;
    float tv    = t2 - t_s * t_s * inv_numel;
    return cross * cross / (iv * tv + 1e-5f);
}

__device__ __forceinline__ void blockred_store(float v, float* partials) {
    __shared__ float red[256];
    red[threadIdx.x] = v;
    __syncthreads();
    for (int o = 128; o > 0; o >>= 1) {
        if (threadIdx.x < o) red[threadIdx.x] += red[threadIdx.x + o];
        __syncthreads();
    }
    if (threadIdx.x == 0) partials[blockIdx.x] = red[0];
}

// ---------------------------------------------------------------------------
// red0: scale0 LNCC from B3 float4s. 204 blocks. partials[0..204).
// ---------------------------------------------------------------------------
__global__ __launch_bounds__(256) void red0(
    const float* __restrict__ B3, float* __restrict__ partials)
{
    constexpr int N3V4 = 57 * 57 * 16;      // 51984 float4 per channel
    int rv = blockIdx.x * 256 + threadIdx.x;
    float v = 0.f;
    if (rv < N3V4) {
        const float4* p = (const float4*)B3;
        float4 s0 = p[rv];
        float4 s1 = p[(size_t)1 * N3V4 + rv];
        float4 s2 = p[(size_t)2 * N3V4 + rv];
        float4 s3 = p[(size_t)3 * N3V4 + rv];
        float4 s4 = p[(size_t)4 * N3V4 + rv];
        const float inv_numel = 1.f / 1728.f;
        int ox = (rv & 15) * 4;
        if (ox + 0 < 57) v += lncc1(s0.x, s1.x, s2.x, s3.x, s4.x, inv_numel);
        if (ox + 1 < 57) v += lncc1(s0.y, s1.y, s2.y, s3.y, s4.y, inv_numel);
        if (ox + 2 < 57) v += lncc1(s0.z, s1.z, s2.z, s3.z, s4.z, inv_numel);
        if (ox + 3 < 57) v += lncc1(s0.w, s1.w, s2.w, s3.w, s4.w, inv_numel);
        v *= 0.1f / 185193.f;
    }
    blockred_store(v, partials);
}

// ---------------------------------------------------------------------------
// red1: scale1. One thread per (output, channel): 8 fully-unrolled loads.
// Block: 255 active threads = 51 outputs x 5 channels (c = t/51, lo = t%51).
// 307 blocks. partials[204..511).
// ---------------------------------------------------------------------------
__global__ __launch_bounds__(256) void red1(
    const float* __restrict__ B3, float* __restrict__ partials)
{
    __shared__ float sh[255];
    const int t  = threadIdx.x;
    const int c  = t / 51;          // 0..4 (t<255)
    const int lo = t - c * 51;      // 0..50
    const int r  = blockIdx.x * 51 + lo;
    float v = 0.f;
    if (t < 255 && r < 15625) {
        int ox = r % 25;
        int q  = r / 25;
        int oy = q % 25;
        int oz = q / 25;
        const float* p = B3 + (((size_t)(c * 57) + 2 * oz) * 57 + 2 * oy) * 64
                         + 2 * ox;
        float acc = 0.f;
#pragma unroll
        for (int iz = 0; iz < 2; ++iz)
#pragma unroll
            for (int iy = 0; iy < 2; ++iy)
#pragma unroll
                for (int ix = 0; ix < 2; ++ix)
                    acc += p[((size_t)(8 * iz) * 57 + 8 * iy) * 64 + 8 * ix];
        sh[t] = acc;
    } else if (t < 255) {
        sh[t] = 0.f;
    }
    __syncthreads();
    if (t < 51 && r < 15625) {
        v = lncc1(sh[t], sh[51 + t], sh[102 + t], sh[153 + t], sh[204 + t],
                  1.f / 13824.f) * (0.3f / 15625.f);
    }
    blockred_store(v, partials + 204);
}

// ---------------------------------------------------------------------------
// red2: scale2. One thread per (output, channel, iz): 16 fully-unrolled loads.
// Block: 240 active = 12 outs x 5 ch x 4 iz (lo = t%12, c = (t/12)/4,
// iz = (t/12)%4). 61 blocks. partials[511..572).
// ---------------------------------------------------------------------------
__global__ __launch_bounds__(256) void red2(
    const float* __restrict__ B3, float* __restrict__ partials)
{
    __shared__ float sh[240];
    __shared__ float sh2[60];
    const int t   = threadIdx.x;
    const int lo  = t % 12;
    const int g   = t / 12;         // 0..19 for t<240
    const int c   = g / 4;
    const int iz  = g % 4;
    const int r   = blockIdx.x * 12 + lo;
    if (t < 240) {
        float acc = 0.f;
        if (r < 729) {
            int ox = r % 9;
            int q  = r / 9;
            int oy = q % 9;
            int oz = q / 9;
            const float* p = B3
                + (((size_t)(c * 57) + (4 * oz + 8 * iz)) * 57 + 4 * oy) * 64
                + 4 * ox;
#pragma unroll
            for (int iy = 0; iy < 4; ++iy)
#pragma unroll
                for (int ix = 0; ix < 4; ++ix)
                    acc += p[(size_t)(8 * iy) * 64 + 8 * ix];
        }
        sh[t] = acc;
    }
    __syncthreads();
    if (t < 60) {                   // t = c*12 + lo view: combine 4 iz slices
        int cc = t / 12, ll = t - cc * 12;
        sh2[t] = sh[(cc * 4 + 0) * 12 + ll] + sh[(cc * 4 + 1) * 12 + ll]
               + sh[(cc * 4 + 2) * 12 + ll] + sh[(cc * 4 + 3) * 12 + ll];
    }
    __syncthreads();
    float v = 0.f;
    if (t < 12 && r < 729) {
        v = lncc1(sh2[t], sh2[12 + t], sh2[24 + t], sh2[36 + t], sh2[48 + t],
                  1.f / 110592.f) * (0.6f / 729.f);
    }
    blockred_store(v, partials + 511);
}

// ---------------------------------------------------------------------------
__global__ __launch_bounds__(256) void finalize_n(
    const float* __restrict__ partials, int n, float* __restrict__ out)
{
    float v = 0.f;
    for (int i = threadIdx.x; i < n; i += 256) v += partials[i];
    __shared__ float red[256];
    red[threadIdx.x] = v;
    __syncthreads();
    for (int o = 128; o > 0; o >>= 1) {
        if (threadIdx.x < o) red[threadIdx.x] += red[threadIdx.x + o];
        __syncthreads();
    }
    if (threadIdx.x == 0) out[0] = 1.0f - red[0];
}

// ------------------- fallback kernels (small-ws path, fp32) ----------------
__global__ void pass1_one(const float* __restrict__ I, const float* __restrict__ T,
                          float* __restrict__ B1, int O, int s, int k, int c) {
    int idx = blockIdx.x * blockDim.x + threadIdx.x;
    if (idx >= IMG * IMG * O) return;
    int ox = idx % O;
    int zy = idx / O;
    const float* pI = I + (size_t)zy * IMG + ox * s;
    const float* pT = T + (size_t)zy * IMG + ox * s;
    float acc = 0.f;
    for (int i = 0; i < k; ++i) {
        float v;
        if (c == 0)      v = pI[2 * i];
        else if (c == 1) v = pT[2 * i];
        else if (c == 2) { float a = pI[2 * i]; v = a * a; }
        else if (c == 3) { float bb = pT[2 * i]; v = bb * bb; }
        else             { v = pI[2 * i] * pT[2 * i]; }
        acc += v;
    }
    B1[idx] = acc;
}

__global__ void pass_y(const float* __restrict__ Bin, float* __restrict__ Bout,
                       int O, int s, int k, int n1, int n2) {
    int idx = blockIdx.x * blockDim.x + threadIdx.x;
    if (idx >= n2) return;
    int ox = idx % O;
    int t  = idx / O;
    int oy = t % O;
    int z  = t / O;
    const float* p = Bin + (size_t)z * IMG * O + (size_t)(oy * s) * O + ox;
    float acc = 0.f;
    for (int j = 0; j < k; ++j) acc += p[(size_t)j * 2 * O];
    Bout[idx] = acc;
}

__global__ void pass_z(const float* __restrict__ Bin, float* __restrict__ Bout,
                       int O, int s, int k, int n2, int n3) {
    int idx = blockIdx.x * blockDim.x + threadIdx.x;
    if (idx >= n3) return;
    int ox = idx % O;
    int t  = idx / O;
    int oy = t % O;
    int oz = t / O;
    const float* p = Bin + (size_t)(oz * s) * O * O + (size_t)oy * O + ox;
    float acc = 0.f;
    for (int l = 0; l < k; ++l) acc += p[(size_t)l * 2 * O * O];
    Bout[idx] = acc;
}

__global__ void reduce_one(const float* __restrict__ B3, int n3, float inv_numel,
                           float wdiv, float* __restrict__ partials) {
    float local = 0.f;
    for (int i = blockIdx.x * 256 + threadIdx.x; i < n3; i += gridDim.x * 256) {
        float i_s = B3[i];
        float t_s = B3[(size_t)n3 + i];
        float i2  = B3[2 * (size_t)n3 + i];
        float t2  = B3[3 * (size_t)n3 + i];
        float it  = B3[4 * (size_t)n3 + i];
        local += wdiv * lncc1(i_s, t_s, i2, t2, it, inv_numel);
    }
    __shared__ float red[256];
    red[threadIdx.x] = local;
    __syncthreads();
    for (int o = 128; o > 0; o >>= 1) {
        if (threadIdx.x < o) red[threadIdx.x] += red[threadIdx.x + o];
        __syncthreads();
    }
    if (threadIdx.x == 0) partials[blockIdx.x] += red[0];
}

__global__ void zero_buf(float* __restrict__ p, int n) {
    int i = blockIdx.x * 256 + threadIdx.x;
    if (i < n) p[i] = 0.f;
}

// ---------------------------------------------------------------------------
extern "C" void kernel_launch(void* const* d_in, const int* in_sizes, int n_in,
                              void* d_out, int out_size, void* d_ws, size_t ws_size,
                              hipStream_t stream) {
    const float* I = (const float*)d_in[0];
    const float* T = (const float*)d_in[1];
    float* out = (float*)d_out;
    float* ws  = (float*)d_ws;

    const size_t szB1f = 5898240;    // B1h as float-equivalents (23.6 MB)
    const size_t szB2f = 1751040;    // B2h as float-equivalents (7.0 MB)
    const size_t szB3  = 1039680;    // fp32 (4.2 MB)
    const size_t need  = (szB1f + szB2f + szB3 + 1024) * sizeof(float); // ~35 MB

    if (ws_size >= need) {
        __half* B1h  = (__half*)ws;
        uint4*  B2h4 = (uint4*)(ws + szB1f);
        float*  B3   = ws + szB1f + szB2f;
        float*  partials = B3 + szB3;
        pass1_s0<<<4608, 256, 0, stream>>>(I, T, B1h);
        passY_s0<<<1710, 256, 0, stream>>>(B1h, B2h4);
        passZc<<<508, 256, 0, stream>>>(B2h4, (float4*)B3);
        red0<<<204, 256, 0, stream>>>(B3, partials);
        red1<<<307, 256, 0, stream>>>(B3, partials);
        red2<<<61, 256, 0, stream>>>(B3, partials);
        finalize_n<<<1, 256, 0, stream>>>(partials, 572, out);
    } else {
        const int   Ks[3] = {12, 24, 48};
        const int   Ss[3] = {3, 6, 12};
        const int   Os[3] = {57, 25, 9};
        const int   N1[3] = {2101248, 921600, 331776};
        const int   N2[3] = {623808, 120000, 15552};
        const int   N3[3] = {185193, 15625, 729};
        const float Wt[3] = {0.1f, 0.3f, 0.6f};

        float* B1 = ws;
        float* B2 = B1 + 2101248;
        float* B3 = B2 + 623808;
        float* partials = B3 + 925965;

        zero_buf<<<1, 256, 0, stream>>>(partials, 256);
        for (int sc = 0; sc < 3; ++sc) {
            int k = Ks[sc], s = Ss[sc], O = Os[sc];
            int n1 = N1[sc], n2 = N2[sc], n3 = N3[sc];
            for (int c = 0; c < 5; ++c) {
                pass1_one<<<(n1 + 255) / 256, 256, 0, stream>>>(I, T, B1, O, s, k, c);
                pass_y<<<(n2 + 255) / 256, 256, 0, stream>>>(B1, B2, O, s, k, n1, n2);
                pass_z<<<(n3 + 255) / 256, 256, 0, stream>>>(B2, B3 + (size_t)c * n3, O, s, k, n2, n3);
            }
            int nblk = (n3 + 255) / 256; if (nblk > 256) nblk = 256;
            reduce_one<<<nblk, 256, 0, stream>>>(B3, n3, 1.f / ((float)k * k * k),
                                                 Wt[sc] / (float)n3, partials);
        }
        finalize_n<<<1, 256, 0, stream>>>(partials, 256, out);
    }
}